// Round 13
// baseline (749.086 us; speedup 1.0000x reference)
//
#include <hip/hip_runtime.h>

// SNN layer on MI355X. i[t,b,o] = sum_k x[b,k,t]*w[k,o]; per-(b,o) sequential
// LIF scan over t; spikes (0/1) fp32 [B,O,T].
//
// Exact fixed-point i8-MFMA path (rounds 7-12 proven, absmax 0.0):
// X=rint(x*2^28) -> 4 signed i8 limbs, W=rint(w*2^15) -> 4 limbs; 13 limb
// pairs (p+q>=2) accumulated exactly in i32 (mfma_i32_16x16x64_i8), combined
// in fp64; eps_i ~ 3e-4 vs ~2e-3 budget.
//
// r8/r9/r11 (32t x 32o wave tile, 2 waves/SIMD): 225-233us, latency-bound
// (1.4-1.9 TB/s, MfmaUtil 20). r12 (16t x 32o, 4 waves/SIMD): 490us, tile
// shrink doubled traffic -> BW-bound. This version: SAME 32t x 32o wave
// tile, but 8 waves/block (512 thr, block tile 128t x 64o),
// launch_bounds(512,4) -> 2 blocks/CU = 4 waves/SIMD: 2x TLP at r9's
// per-wave intensity. Scan in two 64-t phases through one ib[64][66].

#define NB 64
#define NI 512
#define NO 512
#define NT 500

typedef int v4i __attribute__((ext_vector_type(4)));
typedef double d2 __attribute__((ext_vector_type(2)));

#define XT_B_STRIDE 1048576   // bytes per batch in XT
#define P_STRIDE    262144    // bytes per limb plane
#define KB_STRIDE   8192      // bytes per k-block (512 rows * 16B)
#define XT_BYTES    67108864
#define WT_BYTES    1048576

// ============ prep: x transpose+limb-slice (blocks 0..511), w (512..519) ====
__global__ __launch_bounds__(256)
void prep_xw(const float* __restrict__ xg, const float* __restrict__ wg,
             unsigned char* __restrict__ xt, unsigned char* __restrict__ wtb) {
    __shared__ float xs[64][65];
    const int tid = threadIdx.x;
    const int sk  = tid >> 2;
    const int st  = (tid & 3) * 16;
    const int ct  = tid & 63;
    const int ckb = tid >> 6;

    if (blockIdx.x < 512) {
        const int b  = blockIdx.x >> 3;
        const int kc = (blockIdx.x & 7) * 64;
        for (int tc = 0; tc < 512; tc += 64) {
            __syncthreads();
            const float* px = xg + ((size_t)(b * NI + kc + sk)) * NT + tc + st;
            #pragma unroll
            for (int e = 0; e < 16; ++e)
                xs[sk][st + e] = (tc + st + e < NT) ? px[e] : 0.0f;
            __syncthreads();

            unsigned int u0[4] = {0,0,0,0}, u1[4] = {0,0,0,0};
            unsigned int u2[4] = {0,0,0,0}, u3[4] = {0,0,0,0};
            #pragma unroll
            for (int e = 0; e < 16; ++e) {
                const float xv = xs[ckb * 16 + e][ct];
                int X = __float2int_rn(xv * 268435456.0f);    // x * 2^28
                const int a0 = (X << 24) >> 24; X = (X - a0) >> 8;
                const int a1 = (X << 24) >> 24; X = (X - a1) >> 8;
                const int a2 = (X << 24) >> 24; const int a3 = (X - a2) >> 8;
                const int sh = (e & 3) * 8; const int d = e >> 2;
                u0[d] |= (unsigned)(a0 & 0xFF) << sh;
                u1[d] |= (unsigned)(a1 & 0xFF) << sh;
                u2[d] |= (unsigned)(a2 & 0xFF) << sh;
                u3[d] |= (unsigned)(a3 & 0xFF) << sh;
            }
            unsigned char* base = xt + (size_t)b * XT_B_STRIDE
                                  + (size_t)(kc / 16 + ckb) * KB_STRIDE
                                  + (size_t)(tc + ct) * 16;
            *(uint4*)(base)                = make_uint4(u0[0], u0[1], u0[2], u0[3]);
            *(uint4*)(base + P_STRIDE)     = make_uint4(u1[0], u1[1], u1[2], u1[3]);
            *(uint4*)(base + 2 * P_STRIDE) = make_uint4(u2[0], u2[1], u2[2], u2[3]);
            *(uint4*)(base + 3 * P_STRIDE) = make_uint4(u3[0], u3[1], u3[2], u3[3]);
        }
    } else {
        const int kc = (blockIdx.x - 512) * 64;
        for (int oc = 0; oc < 512; oc += 64) {
            __syncthreads();
            const float* pw = wg + (size_t)(kc + sk) * NO + oc + st;
            #pragma unroll
            for (int e = 0; e < 16; e += 4) {
                float4 f = *(const float4*)(pw + e);
                xs[sk][st + e + 0] = f.x; xs[sk][st + e + 1] = f.y;
                xs[sk][st + e + 2] = f.z; xs[sk][st + e + 3] = f.w;
            }
            __syncthreads();

            unsigned int u0[4] = {0,0,0,0}, u1[4] = {0,0,0,0};
            unsigned int u2[4] = {0,0,0,0}, u3[4] = {0,0,0,0};
            #pragma unroll
            for (int e = 0; e < 16; ++e) {
                const float wv = xs[ckb * 16 + e][ct];
                int X = __float2int_rn(wv * 32768.0f);        // w * 2^15
                const int a0 = (X << 24) >> 24; X = (X - a0) >> 8;
                const int a1 = (X << 24) >> 24; X = (X - a1) >> 8;
                const int a2 = (X << 24) >> 24; const int a3 = (X - a2) >> 8;
                const int sh = (e & 3) * 8; const int d = e >> 2;
                u0[d] |= (unsigned)(a0 & 0xFF) << sh;
                u1[d] |= (unsigned)(a1 & 0xFF) << sh;
                u2[d] |= (unsigned)(a2 & 0xFF) << sh;
                u3[d] |= (unsigned)(a3 & 0xFF) << sh;
            }
            unsigned char* base = wtb + (size_t)(kc / 16 + ckb) * KB_STRIDE
                                  + (size_t)(oc + ct) * 16;
            *(uint4*)(base)                = make_uint4(u0[0], u0[1], u0[2], u0[3]);
            *(uint4*)(base + P_STRIDE)     = make_uint4(u1[0], u1[1], u1[2], u1[3]);
            *(uint4*)(base + 2 * P_STRIDE) = make_uint4(u2[0], u2[1], u2[2], u2[3]);
            *(uint4*)(base + 3 * P_STRIDE) = make_uint4(u3[0], u3[1], u3[2], u3[3]);
        }
    }
}

// == main: 8-wave, 32t x 32o wave tile (4 waves/SIMD TLP) i8-MFMA + scan ==
#define MFMA_I8(a, b, c) __builtin_amdgcn_mfma_i32_16x16x64_i8(a, b, c, 0, 0, 0)

__global__ __launch_bounds__(512, 4)
void snn_i8v7(const unsigned char* __restrict__ xt,
              const unsigned char* __restrict__ wtb,
              float* __restrict__ yg) {
    __shared__ double ib[64][66];        // 33,792 B (reused for both t-halves)

    const int tid  = threadIdx.x;
    const int lane = tid & 63;
    const int wv   = tid >> 6;      // wave 0..7
    const int wt   = wv & 3;        // t-quarter of 128-t chunk (32 rows each)
    const int wo   = wv >> 2;       // o-half (32 cols)
    const int lr   = lane & 15;
    const int lg   = lane >> 4;

    // XCD swizzle (proven): 8 o-tiles of one batch share an XCD.
    const int L  = blockIdx.x;
    const int b  = (L & 7) + ((L >> 6) << 3);
    const int o0 = ((L >> 3) & 7) * 64;

    const unsigned char* xb = xt + (size_t)b * XT_B_STRIDE;
    const unsigned char* wb = wtb + (size_t)o0 * 16;

    const double alpha = 0.001 / 50.0;
    double v = 0.0;                 // scan state (lanes<8 of each wave)

    for (int tc = 0; tc < 4; ++tc) {            // 4 chunks of 128 t (512 padded)
        v4i acc0[2][2], acc1[2][2], acc2[2][2], acc3[2][2], acc4[2][2];
        #pragma unroll
        for (int ta = 0; ta < 2; ++ta)
            #pragma unroll
            for (int oc = 0; oc < 2; ++oc) {
                acc0[ta][oc] = (v4i){0,0,0,0}; acc1[ta][oc] = (v4i){0,0,0,0};
                acc2[ta][oc] = (v4i){0,0,0,0}; acc3[ta][oc] = (v4i){0,0,0,0};
                acc4[ta][oc] = (v4i){0,0,0,0};
            }

        const int tbase = tc * 128 + wt * 32;    // wave's 32-t strip in XT

        // ---- K loop: plain register-direct loads (r8-proven); TLP hides lat.
        for (int kw = 0; kw < 8; ++kw) {         // 8 windows x 64 k
            const size_t kb0 = (size_t)(kw * 4 + lg) * KB_STRIDE;
            v4i aF[2][4], bF[2][4];
            #pragma unroll
            for (int p = 0; p < 4; ++p) {
                const size_t pp = (size_t)p * P_STRIDE + kb0;
                #pragma unroll
                for (int ta = 0; ta < 2; ++ta)
                    aF[ta][p] = *(const v4i*)(xb + pp
                                 + (size_t)(tbase + ta * 16 + lr) * 16);
                #pragma unroll
                for (int oc = 0; oc < 2; ++oc)
                    bF[oc][p] = *(const v4i*)(wb + pp
                                 + (size_t)(wo * 32 + oc * 16 + lr) * 16);
            }
            #pragma unroll
            for (int ta = 0; ta < 2; ++ta)
                #pragma unroll
                for (int oc = 0; oc < 2; ++oc) {
                    acc0[ta][oc] = MFMA_I8(aF[ta][0], bF[oc][2], acc0[ta][oc]);
                    acc0[ta][oc] = MFMA_I8(aF[ta][1], bF[oc][1], acc0[ta][oc]);
                    acc0[ta][oc] = MFMA_I8(aF[ta][2], bF[oc][0], acc0[ta][oc]);
                    acc1[ta][oc] = MFMA_I8(aF[ta][0], bF[oc][3], acc1[ta][oc]);
                    acc1[ta][oc] = MFMA_I8(aF[ta][1], bF[oc][2], acc1[ta][oc]);
                    acc1[ta][oc] = MFMA_I8(aF[ta][2], bF[oc][1], acc1[ta][oc]);
                    acc1[ta][oc] = MFMA_I8(aF[ta][3], bF[oc][0], acc1[ta][oc]);
                    acc2[ta][oc] = MFMA_I8(aF[ta][1], bF[oc][3], acc2[ta][oc]);
                    acc2[ta][oc] = MFMA_I8(aF[ta][2], bF[oc][2], acc2[ta][oc]);
                    acc2[ta][oc] = MFMA_I8(aF[ta][3], bF[oc][1], acc2[ta][oc]);
                    acc3[ta][oc] = MFMA_I8(aF[ta][2], bF[oc][3], acc3[ta][oc]);
                    acc3[ta][oc] = MFMA_I8(aF[ta][3], bF[oc][2], acc3[ta][oc]);
                    acc4[ta][oc] = MFMA_I8(aF[ta][3], bF[oc][3], acc4[ta][oc]);
                }
        }

        // ---- two 64-t phases: write ib + scan (ib reused) ----
        #pragma unroll
        for (int ph = 0; ph < 2; ++ph) {
            __syncthreads();   // prior phase's scan reads (or prior chunk) done
            if ((wt >> 1) == ph) {
                // D: col = lane&15 (o), row = 4*(lane>>4)+reg -- HW-verified.
                const int trow = (wt & 1) * 32;
                #pragma unroll
                for (int ta = 0; ta < 2; ++ta)
                    #pragma unroll
                    for (int oc = 0; oc < 2; ++oc) {
                        const int o_loc = wo * 32 + oc * 16 + lr;
                        #pragma unroll
                        for (int r = 0; r < 4; ++r) {
                            const double iv =
                                  (double)acc0[ta][oc][r] * 0x1p-27
                                + (double)acc1[ta][oc][r] * 0x1p-19
                                + (double)acc2[ta][oc][r] * 0x1p-11
                                + (double)acc3[ta][oc][r] * 0x1p-3
                                + (double)acc4[ta][oc][r] * 0x1p+5;
                            ib[trow + ta * 16 + lg * 4 + r][o_loc] = iv;
                        }
                    }
            }
            __syncthreads();

            // scan: 8 waves x 8 o-channels (lanes 0..7), 64 t this phase
            if (lane < 8) {
                const int ol = wv * 8 + lane;            // local o 0..63
                const int t0g = tc * 128 + ph * 64;
                float* py = yg + ((size_t)(b * NO) + o0 + ol) * NT + t0g;
                #pragma unroll
                for (int tb = 0; tb < 4; ++tb) {
                    double iv[16];
                    #pragma unroll
                    for (int u = 0; u < 16; ++u) iv[u] = ib[tb * 16 + u][ol];
                    float fv[16];
                    #pragma unroll
                    for (int u = 0; u < 16; ++u) {
                        v += (iv[u] - v) * alpha;
                        const bool s = (v >= 1.0);
                        fv[u] = s ? 1.0f : 0.0f;
                        if (s) v = 0.0;
                    }
                    const int tg = t0g + tb * 16;
                    #pragma unroll
                    for (int q = 0; q < 4; ++q)
                        if (tg + q * 4 < NT)
                            *(float4*)(py + tb * 16 + q * 4) =
                                make_float4(fv[q*4], fv[q*4+1], fv[q*4+2], fv[q*4+3]);
                }
            }
        }
    }
}

// ============ fallback: round-4 fused fp64 kernel (proven, ws-free) ============
#define OT 64
#define TT 64
#define KC 32
#define TP (TT + 2)
#define OP (OT + 2)

__global__ __launch_bounds__(256, 2)
void snn_v2(const float* __restrict__ xg, const float* __restrict__ wg,
            float* __restrict__ yg) {
    __shared__ double smem[KC * TP + KC * OP];
    double (*xs)[TP]  = (double(*)[TP])smem;
    double (*wsh)[OP] = (double(*)[OP])(smem + KC * TP);
    double (*ib)[OP]  = (double(*)[OP])smem;

    const int tid = threadIdx.x;
    const int p2  = (tid & 31) * 2;
    const int t0  = (tid >> 5) * 8;
    const int L   = blockIdx.x;
    const int b   = (L & 7) + ((L >> 6) << 3);
    const int o0  = ((L >> 3) & 7) * OT;
    const int sk  = tid >> 3;
    const int se  = (tid & 7) * 8;
    const double alpha = 0.001 / 50.0;
    double v = 0.0;

    for (int tc = 0; tc < NT; tc += TT) {
        const int tlim = (NT - tc < TT) ? (NT - tc) : TT;
        double a0[8], a1[8];
        #pragma unroll
        for (int j = 0; j < 8; ++j) { a0[j] = 0.0; a1[j] = 0.0; }

        for (int kc = 0; kc < NI; kc += KC) {
            __syncthreads();
            {
                const float* px = xg + ((size_t)(b * NI + kc + sk)) * NT + tc + se;
                double* dx = &xs[sk][se];
                if (tlim == TT) {
                    #pragma unroll
                    for (int e = 0; e < 2; ++e) {
                        float4 f = ((const float4*)px)[e];
                        d2 lo = {(double)f.x, (double)f.y};
                        d2 hi = {(double)f.z, (double)f.w};
                        *(d2*)(dx + e * 4) = lo; *(d2*)(dx + e * 4 + 2) = hi;
                    }
                } else {
                    #pragma unroll
                    for (int e = 0; e < 8; ++e) {
                        double val = 0.0;
                        if (se + e < tlim) val = (double)px[e];
                        dx[e] = val;
                    }
                }
            }
            {
                const float* pw = wg + (size_t)(kc + sk) * NO + o0 + se;
                double* dw = &wsh[sk][se];
                #pragma unroll
                for (int e = 0; e < 2; ++e) {
                    float4 f = ((const float4*)pw)[e];
                    d2 lo = {(double)f.x, (double)f.y};
                    d2 hi = {(double)f.z, (double)f.w};
                    *(d2*)(dw + e * 4) = lo; *(d2*)(dw + e * 4 + 2) = hi;
                }
            }
            __syncthreads();
            #pragma unroll 4
            for (int k = 0; k < KC; ++k) {
                const d2 w2 = *(const d2*)&wsh[k][p2];
                double x8[8];
                #pragma unroll
                for (int e = 0; e < 4; ++e)
                    *(d2*)&x8[e * 2] = *(const d2*)&xs[k][t0 + e * 2];
                #pragma unroll
                for (int j = 0; j < 8; ++j) {
                    a0[j] += x8[j] * w2[0];
                    a1[j] += x8[j] * w2[1];
                }
            }
        }
        __syncthreads();
        #pragma unroll
        for (int j = 0; j < 8; ++j) {
            d2 c = {a0[j], a1[j]};
            *(d2*)&ib[t0 + j][p2] = c;
        }
        __syncthreads();
        if (tid < 64) {
            float* py = yg + ((size_t)(b * NO + o0 + tid)) * NT + tc;
            for (int tb = 0; tb < TT; tb += 16) {
                double iv[16];
                #pragma unroll
                for (int u = 0; u < 16; ++u) iv[u] = ib[tb + u][tid];
                float fv[16];
                #pragma unroll
                for (int u = 0; u < 16; ++u) {
                    v += (iv[u] - v) * alpha;
                    const bool s = (v >= 1.0);
                    fv[u] = s ? 1.0f : 0.0f;
                    if (s) v = 0.0;
                }
                #pragma unroll
                for (int q = 0; q < 4; ++q)
                    if (tb + q * 4 < tlim)
                        *(float4*)(py + tb + q * 4) =
                            make_float4(fv[q*4], fv[q*4+1], fv[q*4+2], fv[q*4+3]);
            }
        }
    }
}

extern "C" void kernel_launch(void* const* d_in, const int* in_sizes, int n_in,
                              void* d_out, int out_size, void* d_ws, size_t ws_size,
                              hipStream_t stream) {
    const float* x = (const float*)d_in[0];   // [64, 512, 500]
    const float* w = (const float*)d_in[1];   // [512, 512]
    float* y = (float*)d_out;                 // [64, 512, 500]
    (void)in_sizes; (void)n_in; (void)out_size;

    const size_t need = (size_t)XT_BYTES + WT_BYTES;   // 68,157,440 B
    if (ws_size >= need) {
        unsigned char* xt  = (unsigned char*)d_ws;
        unsigned char* wtb = (unsigned char*)d_ws + XT_BYTES;
        prep_xw<<<520, 256, 0, stream>>>(x, w, xt, wtb);
        snn_i8v7<<<512, 512, 0, stream>>>(xt, wtb, y);
    } else {
        snn_v2<<<512, 256, 0, stream>>>(x, w, y);      // proven fallback
    }
}

// Round 14
// 634.935 us; speedup vs baseline: 1.1798x; 1.1798x over previous
//
#include <hip/hip_runtime.h>

// SNN layer on MI355X. i[t,b,o] = sum_k x[b,k,t]*w[k,o]; per-(b,o) sequential
// LIF scan over t; spikes (0/1) fp32 [B,O,T].
//
// Exact fixed-point i8-MFMA path (rounds 7-13 proven, absmax 0.0):
// X=rint(x*2^28) -> 4 signed i8 limbs, W=rint(w*2^15) -> 4 limbs; 13 limb
// pairs (p+q>=2) accumulated exactly in i32 (mfma_i32_16x16x64_i8), combined
// in fp64; eps_i ~ 3e-4 vs ~2e-3 budget.
//
// r8-r13 synthesis: 32t x 32o wave tile @ 2 waves/SIMD is latency-bound at
// ~225us; ILP tricks defeated by compiler; TLP failed when it shrank the
// tile (r12: traffic 2x) or broke regalloc (r13: forced 64 VGPR, 1.1GB
// scratch). The grid (512 = 2 blocks/CU), pinned by the fused scan's
// t-dependency, was the occupancy limit -- NOT resources. This version:
// t-split GEMM (grid 1024 = 4 blocks/CU = 4 waves/SIMD, same wave tile,
// no LDS, no barriers) -> iw fp64 in ws; separate r5-style streaming scan.
// Fallbacks: ws>=68MB -> r11 fused path (225us); else fp64 snn_v2.

#define NB 64
#define NI 512
#define NO 512
#define NT 500
#define BO (NB * NO)          // 32768 channels

typedef int v4i __attribute__((ext_vector_type(4)));
typedef double d2 __attribute__((ext_vector_type(2)));

#define XT_B_STRIDE 1048576   // bytes per batch in XT
#define P_STRIDE    262144    // bytes per limb plane
#define KB_STRIDE   8192      // bytes per k-block (512 rows * 16B)
#define XT_BYTES    67108864
#define WT_BYTES    1048576
#define IW_BYTES    ((size_t)NT * BO * 8)          // 131,072,000
#define WS_SMALL    ((size_t)XT_BYTES + WT_BYTES)  //  68,157,440
#define WS_FULL     (WS_SMALL + IW_BYTES)          // 199,229,440

// ============ prep: x transpose+limb-slice (blocks 0..511), w (512..519) ====
__global__ __launch_bounds__(256)
void prep_xw(const float* __restrict__ xg, const float* __restrict__ wg,
             unsigned char* __restrict__ xt, unsigned char* __restrict__ wtb) {
    __shared__ float xs[64][65];
    const int tid = threadIdx.x;
    const int sk  = tid >> 2;
    const int st  = (tid & 3) * 16;
    const int ct  = tid & 63;
    const int ckb = tid >> 6;

    if (blockIdx.x < 512) {
        const int b  = blockIdx.x >> 3;
        const int kc = (blockIdx.x & 7) * 64;
        for (int tc = 0; tc < 512; tc += 64) {
            __syncthreads();
            const float* px = xg + ((size_t)(b * NI + kc + sk)) * NT + tc + st;
            #pragma unroll
            for (int e = 0; e < 16; ++e)
                xs[sk][st + e] = (tc + st + e < NT) ? px[e] : 0.0f;
            __syncthreads();

            unsigned int u0[4] = {0,0,0,0}, u1[4] = {0,0,0,0};
            unsigned int u2[4] = {0,0,0,0}, u3[4] = {0,0,0,0};
            #pragma unroll
            for (int e = 0; e < 16; ++e) {
                const float xv = xs[ckb * 16 + e][ct];
                int X = __float2int_rn(xv * 268435456.0f);    // x * 2^28
                const int a0 = (X << 24) >> 24; X = (X - a0) >> 8;
                const int a1 = (X << 24) >> 24; X = (X - a1) >> 8;
                const int a2 = (X << 24) >> 24; const int a3 = (X - a2) >> 8;
                const int sh = (e & 3) * 8; const int d = e >> 2;
                u0[d] |= (unsigned)(a0 & 0xFF) << sh;
                u1[d] |= (unsigned)(a1 & 0xFF) << sh;
                u2[d] |= (unsigned)(a2 & 0xFF) << sh;
                u3[d] |= (unsigned)(a3 & 0xFF) << sh;
            }
            unsigned char* base = xt + (size_t)b * XT_B_STRIDE
                                  + (size_t)(kc / 16 + ckb) * KB_STRIDE
                                  + (size_t)(tc + ct) * 16;
            *(uint4*)(base)                = make_uint4(u0[0], u0[1], u0[2], u0[3]);
            *(uint4*)(base + P_STRIDE)     = make_uint4(u1[0], u1[1], u1[2], u1[3]);
            *(uint4*)(base + 2 * P_STRIDE) = make_uint4(u2[0], u2[1], u2[2], u2[3]);
            *(uint4*)(base + 3 * P_STRIDE) = make_uint4(u3[0], u3[1], u3[2], u3[3]);
        }
    } else {
        const int kc = (blockIdx.x - 512) * 64;
        for (int oc = 0; oc < 512; oc += 64) {
            __syncthreads();
            const float* pw = wg + (size_t)(kc + sk) * NO + oc + st;
            #pragma unroll
            for (int e = 0; e < 16; e += 4) {
                float4 f = *(const float4*)(pw + e);
                xs[sk][st + e + 0] = f.x; xs[sk][st + e + 1] = f.y;
                xs[sk][st + e + 2] = f.z; xs[sk][st + e + 3] = f.w;
            }
            __syncthreads();

            unsigned int u0[4] = {0,0,0,0}, u1[4] = {0,0,0,0};
            unsigned int u2[4] = {0,0,0,0}, u3[4] = {0,0,0,0};
            #pragma unroll
            for (int e = 0; e < 16; ++e) {
                const float wv = xs[ckb * 16 + e][ct];
                int X = __float2int_rn(wv * 32768.0f);        // w * 2^15
                const int a0 = (X << 24) >> 24; X = (X - a0) >> 8;
                const int a1 = (X << 24) >> 24; X = (X - a1) >> 8;
                const int a2 = (X << 24) >> 24; const int a3 = (X - a2) >> 8;
                const int sh = (e & 3) * 8; const int d = e >> 2;
                u0[d] |= (unsigned)(a0 & 0xFF) << sh;
                u1[d] |= (unsigned)(a1 & 0xFF) << sh;
                u2[d] |= (unsigned)(a2 & 0xFF) << sh;
                u3[d] |= (unsigned)(a3 & 0xFF) << sh;
            }
            unsigned char* base = wtb + (size_t)(kc / 16 + ckb) * KB_STRIDE
                                  + (size_t)(oc + ct) * 16;
            *(uint4*)(base)                = make_uint4(u0[0], u0[1], u0[2], u0[3]);
            *(uint4*)(base + P_STRIDE)     = make_uint4(u1[0], u1[1], u1[2], u1[3]);
            *(uint4*)(base + 2 * P_STRIDE) = make_uint4(u2[0], u2[1], u2[2], u2[3]);
            *(uint4*)(base + 3 * P_STRIDE) = make_uint4(u3[0], u3[1], u3[2], u3[3]);
        }
    }
}

#define MFMA_I8(a, b, c) __builtin_amdgcn_mfma_i32_16x16x64_i8(a, b, c, 0, 0, 0)

// ===== K1: t-split i8-MFMA GEMM -> iw fp64. No LDS, no barriers, 4 wv/SIMD ====
__global__ __launch_bounds__(256, 4)
void snn_i8g(const unsigned char* __restrict__ xt,
             const unsigned char* __restrict__ wtb,
             double* __restrict__ iw) {
    const int tid  = threadIdx.x;
    const int lane = tid & 63;
    const int wv   = tid >> 6;      // wave 0..3
    const int wt   = wv & 1;        // t-half of 64-t chunk (32 rows)
    const int wo   = wv >> 1;       // o-half (32 cols)
    const int lr   = lane & 15;
    const int lg   = lane >> 4;

    // bijective XCD swizzle (1024 blocks): a batch's 16 blocks share an XCD.
    const int L  = blockIdx.x;
    const int wg = (L & 7) * 128 + (L >> 3);
    const int b  = wg >> 4;             // 16 blocks per batch (8 o x 2 t-half)
    const int o0 = ((wg >> 1) & 7) * 64;
    const int th = wg & 1;              // t-half: t in [th*256, th*256+256)

    const unsigned char* xb = xt + (size_t)b * XT_B_STRIDE;
    const unsigned char* wb = wtb + (size_t)o0 * 16;

    for (int tc2 = 0; tc2 < 4; ++tc2) {         // 4 chunks of 64 t
        const int tch   = th * 4 + tc2;
        const int tbase = tch * 64 + wt * 32;   // wave's 32-t strip in XT

        v4i acc0[2][2], acc1[2][2], acc2[2][2], acc3[2][2], acc4[2][2];
        #pragma unroll
        for (int ta = 0; ta < 2; ++ta)
            #pragma unroll
            for (int oc = 0; oc < 2; ++oc) {
                acc0[ta][oc] = (v4i){0,0,0,0}; acc1[ta][oc] = (v4i){0,0,0,0};
                acc2[ta][oc] = (v4i){0,0,0,0}; acc3[ta][oc] = (v4i){0,0,0,0};
                acc4[ta][oc] = (v4i){0,0,0,0};
            }

        for (int kw = 0; kw < 8; ++kw) {        // plain r8-style loads; TLP hides
            const size_t kb0 = (size_t)(kw * 4 + lg) * KB_STRIDE;
            v4i aF[2][4], bF[2][4];
            #pragma unroll
            for (int p = 0; p < 4; ++p) {
                const size_t pp = (size_t)p * P_STRIDE + kb0;
                #pragma unroll
                for (int ta = 0; ta < 2; ++ta)
                    aF[ta][p] = *(const v4i*)(xb + pp
                                 + (size_t)(tbase + ta * 16 + lr) * 16);
                #pragma unroll
                for (int oc = 0; oc < 2; ++oc)
                    bF[oc][p] = *(const v4i*)(wb + pp
                                 + (size_t)(wo * 32 + oc * 16 + lr) * 16);
            }
            #pragma unroll
            for (int ta = 0; ta < 2; ++ta)
                #pragma unroll
                for (int oc = 0; oc < 2; ++oc) {
                    acc0[ta][oc] = MFMA_I8(aF[ta][0], bF[oc][2], acc0[ta][oc]);
                    acc0[ta][oc] = MFMA_I8(aF[ta][1], bF[oc][1], acc0[ta][oc]);
                    acc0[ta][oc] = MFMA_I8(aF[ta][2], bF[oc][0], acc0[ta][oc]);
                    acc1[ta][oc] = MFMA_I8(aF[ta][0], bF[oc][3], acc1[ta][oc]);
                    acc1[ta][oc] = MFMA_I8(aF[ta][1], bF[oc][2], acc1[ta][oc]);
                    acc1[ta][oc] = MFMA_I8(aF[ta][2], bF[oc][1], acc1[ta][oc]);
                    acc1[ta][oc] = MFMA_I8(aF[ta][3], bF[oc][0], acc1[ta][oc]);
                    acc2[ta][oc] = MFMA_I8(aF[ta][1], bF[oc][3], acc2[ta][oc]);
                    acc2[ta][oc] = MFMA_I8(aF[ta][2], bF[oc][2], acc2[ta][oc]);
                    acc2[ta][oc] = MFMA_I8(aF[ta][3], bF[oc][1], acc2[ta][oc]);
                    acc3[ta][oc] = MFMA_I8(aF[ta][2], bF[oc][3], acc3[ta][oc]);
                    acc3[ta][oc] = MFMA_I8(aF[ta][3], bF[oc][2], acc3[ta][oc]);
                    acc4[ta][oc] = MFMA_I8(aF[ta][3], bF[oc][3], acc4[ta][oc]);
                }
        }

        // combine limbs in fp64; write straight to iw[t][b*NO+o] (128B segs)
        #pragma unroll
        for (int ta = 0; ta < 2; ++ta)
            #pragma unroll
            for (int oc = 0; oc < 2; ++oc) {
                const int o_loc = wo * 32 + oc * 16 + lr;
                #pragma unroll
                for (int r = 0; r < 4; ++r) {
                    const int t = tbase + ta * 16 + lg * 4 + r;
                    if (t < NT) {
                        const double iv =
                              (double)acc0[ta][oc][r] * 0x1p-27
                            + (double)acc1[ta][oc][r] * 0x1p-19
                            + (double)acc2[ta][oc][r] * 0x1p-11
                            + (double)acc3[ta][oc][r] * 0x1p-3
                            + (double)acc4[ta][oc][r] * 0x1p+5;
                        iw[(size_t)t * BO + b * NO + o0 + o_loc] = iv;
                    }
                }
            }
    }
}

// ===== K2: sequential LIF scan (r5-proven) =====
#define SB 20                 // 500 = 25*20
__global__ __launch_bounds__(64)
void snn_scan(const double* __restrict__ iw, float* __restrict__ yg) {
    const int ch = blockIdx.x * 64 + threadIdx.x;   // b*512+o
    const double alpha = 0.001 / 50.0;
    double v = 0.0;
    float* py = yg + (size_t)ch * NT;

    for (int tb = 0; tb < NT; tb += SB) {
        double iv[SB];
        #pragma unroll
        for (int u = 0; u < SB; ++u) iv[u] = iw[(size_t)(tb + u) * BO + ch];
        float fv[SB];
        #pragma unroll
        for (int u = 0; u < SB; ++u) {
            v += (iv[u] - v) * alpha;
            const bool s = (v >= 1.0);
            fv[u] = s ? 1.0f : 0.0f;
            if (s) v = 0.0;
        }
        #pragma unroll
        for (int q = 0; q < SB / 4; ++q)
            *(float4*)(py + tb + 4 * q) =
                make_float4(fv[4*q], fv[4*q+1], fv[4*q+2], fv[4*q+3]);
    }
}

// ===== fallback A: r11 fused kernel (225us proven) =====
__global__ __launch_bounds__(256, 2)
void snn_i8v5(const unsigned char* __restrict__ xt,
              const unsigned char* __restrict__ wtb,
              float* __restrict__ yg) {
    __shared__ double ib[64][66];

    const int tid  = threadIdx.x;
    const int lane = tid & 63;
    const int wv   = tid >> 6;
    const int wt   = wv & 1;
    const int wo   = wv >> 1;
    const int lr   = lane & 15;
    const int lg   = lane >> 4;

    const int L  = blockIdx.x;
    const int b  = (L & 7) + ((L >> 6) << 3);
    const int o0 = ((L >> 3) & 7) * 64;

    const unsigned char* xb = xt + (size_t)b * XT_B_STRIDE;
    const unsigned char* wb = wtb + (size_t)o0 * 16;

    const double alpha = 0.001 / 50.0;
    double v = 0.0;

    for (int tc = 0; tc < 8; ++tc) {
        v4i acc0[2][2], acc1[2][2], acc2[2][2], acc3[2][2], acc4[2][2];
        #pragma unroll
        for (int ta = 0; ta < 2; ++ta)
            #pragma unroll
            for (int oc = 0; oc < 2; ++oc) {
                acc0[ta][oc] = (v4i){0,0,0,0}; acc1[ta][oc] = (v4i){0,0,0,0};
                acc2[ta][oc] = (v4i){0,0,0,0}; acc3[ta][oc] = (v4i){0,0,0,0};
                acc4[ta][oc] = (v4i){0,0,0,0};
            }
        const int tbase = tc * 64 + wt * 32;

        for (int kw = 0; kw < 8; ++kw) {
            const size_t kb0 = (size_t)(kw * 4 + lg) * KB_STRIDE;
            v4i aF[2][4], bF[2][4];
            #pragma unroll
            for (int p = 0; p < 4; ++p) {
                const size_t pp = (size_t)p * P_STRIDE + kb0;
                #pragma unroll
                for (int ta = 0; ta < 2; ++ta)
                    aF[ta][p] = *(const v4i*)(xb + pp
                                 + (size_t)(tbase + ta * 16 + lr) * 16);
                #pragma unroll
                for (int oc = 0; oc < 2; ++oc)
                    bF[oc][p] = *(const v4i*)(wb + pp
                                 + (size_t)(wo * 32 + oc * 16 + lr) * 16);
            }
            #pragma unroll
            for (int ta = 0; ta < 2; ++ta)
                #pragma unroll
                for (int oc = 0; oc < 2; ++oc) {
                    acc0[ta][oc] = MFMA_I8(aF[ta][0], bF[oc][2], acc0[ta][oc]);
                    acc0[ta][oc] = MFMA_I8(aF[ta][1], bF[oc][1], acc0[ta][oc]);
                    acc0[ta][oc] = MFMA_I8(aF[ta][2], bF[oc][0], acc0[ta][oc]);
                    acc1[ta][oc] = MFMA_I8(aF[ta][0], bF[oc][3], acc1[ta][oc]);
                    acc1[ta][oc] = MFMA_I8(aF[ta][1], bF[oc][2], acc1[ta][oc]);
                    acc1[ta][oc] = MFMA_I8(aF[ta][2], bF[oc][1], acc1[ta][oc]);
                    acc1[ta][oc] = MFMA_I8(aF[ta][3], bF[oc][0], acc1[ta][oc]);
                    acc2[ta][oc] = MFMA_I8(aF[ta][1], bF[oc][3], acc2[ta][oc]);
                    acc2[ta][oc] = MFMA_I8(aF[ta][2], bF[oc][2], acc2[ta][oc]);
                    acc2[ta][oc] = MFMA_I8(aF[ta][3], bF[oc][1], acc2[ta][oc]);
                    acc3[ta][oc] = MFMA_I8(aF[ta][2], bF[oc][3], acc3[ta][oc]);
                    acc3[ta][oc] = MFMA_I8(aF[ta][3], bF[oc][2], acc3[ta][oc]);
                    acc4[ta][oc] = MFMA_I8(aF[ta][3], bF[oc][3], acc4[ta][oc]);
                }
        }

        __syncthreads();
        #pragma unroll
        for (int ta = 0; ta < 2; ++ta)
            #pragma unroll
            for (int oc = 0; oc < 2; ++oc) {
                const int o_loc = wo * 32 + oc * 16 + lr;
                #pragma unroll
                for (int r = 0; r < 4; ++r) {
                    const double iv =
                          (double)acc0[ta][oc][r] * 0x1p-27
                        + (double)acc1[ta][oc][r] * 0x1p-19
                        + (double)acc2[ta][oc][r] * 0x1p-11
                        + (double)acc3[ta][oc][r] * 0x1p-3
                        + (double)acc4[ta][oc][r] * 0x1p+5;
                    ib[wt * 32 + ta * 16 + lg * 4 + r][o_loc] = iv;
                }
            }
        __syncthreads();

        if (lane < 16) {
            const int ol = wv * 16 + lane;
            float* py = yg + ((size_t)(b * NO) + o0 + ol) * NT + tc * 64;
            #pragma unroll
            for (int tb = 0; tb < 4; ++tb) {
                double iv[16];
                #pragma unroll
                for (int u = 0; u < 16; ++u) iv[u] = ib[tb * 16 + u][ol];
                float fv[16];
                #pragma unroll
                for (int u = 0; u < 16; ++u) {
                    v += (iv[u] - v) * alpha;
                    const bool s = (v >= 1.0);
                    fv[u] = s ? 1.0f : 0.0f;
                    if (s) v = 0.0;
                }
                const int tg = tc * 64 + tb * 16;
                #pragma unroll
                for (int q = 0; q < 4; ++q)
                    if (tg + q * 4 < NT)
                        *(float4*)(py + tb * 16 + q * 4) =
                            make_float4(fv[q*4], fv[q*4+1], fv[q*4+2], fv[q*4+3]);
            }
        }
    }
}

// ===== fallback B: r4 fused fp64 kernel (ws-free, proven) =====
#define OT 64
#define TT 64
#define KC 32
#define TP (TT + 2)
#define OP (OT + 2)

__global__ __launch_bounds__(256, 2)
void snn_v2(const float* __restrict__ xg, const float* __restrict__ wg,
            float* __restrict__ yg) {
    __shared__ double smem[KC * TP + KC * OP];
    double (*xs)[TP]  = (double(*)[TP])smem;
    double (*wsh)[OP] = (double(*)[OP])(smem + KC * TP);
    double (*ib)[OP]  = (double(*)[OP])smem;

    const int tid = threadIdx.x;
    const int p2  = (tid & 31) * 2;
    const int t0  = (tid >> 5) * 8;
    const int L   = blockIdx.x;
    const int b   = (L & 7) + ((L >> 6) << 3);
    const int o0  = ((L >> 3) & 7) * OT;
    const int sk  = tid >> 3;
    const int se  = (tid & 7) * 8;
    const double alpha = 0.001 / 50.0;
    double v = 0.0;

    for (int tc = 0; tc < NT; tc += TT) {
        const int tlim = (NT - tc < TT) ? (NT - tc) : TT;
        double a0[8], a1[8];
        #pragma unroll
        for (int j = 0; j < 8; ++j) { a0[j] = 0.0; a1[j] = 0.0; }

        for (int kc = 0; kc < NI; kc += KC) {
            __syncthreads();
            {
                const float* px = xg + ((size_t)(b * NI + kc + sk)) * NT + tc + se;
                double* dx = &xs[sk][se];
                if (tlim == TT) {
                    #pragma unroll
                    for (int e = 0; e < 2; ++e) {
                        float4 f = ((const float4*)px)[e];
                        d2 lo = {(double)f.x, (double)f.y};
                        d2 hi = {(double)f.z, (double)f.w};
                        *(d2*)(dx + e * 4) = lo; *(d2*)(dx + e * 4 + 2) = hi;
                    }
                } else {
                    #pragma unroll
                    for (int e = 0; e < 8; ++e) {
                        double val = 0.0;
                        if (se + e < tlim) val = (double)px[e];
                        dx[e] = val;
                    }
                }
            }
            {
                const float* pw = wg + (size_t)(kc + sk) * NO + o0 + se;
                double* dw = &wsh[sk][se];
                #pragma unroll
                for (int e = 0; e < 2; ++e) {
                    float4 f = ((const float4*)pw)[e];
                    d2 lo = {(double)f.x, (double)f.y};
                    d2 hi = {(double)f.z, (double)f.w};
                    *(d2*)(dw + e * 4) = lo; *(d2*)(dw + e * 4 + 2) = hi;
                }
            }
            __syncthreads();
            #pragma unroll 4
            for (int k = 0; k < KC; ++k) {
                const d2 w2 = *(const d2*)&wsh[k][p2];
                double x8[8];
                #pragma unroll
                for (int e = 0; e < 4; ++e)
                    *(d2*)&x8[e * 2] = *(const d2*)&xs[k][t0 + e * 2];
                #pragma unroll
                for (int j = 0; j < 8; ++j) {
                    a0[j] += x8[j] * w2[0];
                    a1[j] += x8[j] * w2[1];
                }
            }
        }
        __syncthreads();
        #pragma unroll
        for (int j = 0; j < 8; ++j) {
            d2 c = {a0[j], a1[j]};
            *(d2*)&ib[t0 + j][p2] = c;
        }
        __syncthreads();
        if (tid < 64) {
            float* py = yg + ((size_t)(b * NO + o0 + tid)) * NT + tc;
            for (int tb = 0; tb < TT; tb += 16) {
                double iv[16];
                #pragma unroll
                for (int u = 0; u < 16; ++u) iv[u] = ib[tb + u][tid];
                float fv[16];
                #pragma unroll
                for (int u = 0; u < 16; ++u) {
                    v += (iv[u] - v) * alpha;
                    const bool s = (v >= 1.0);
                    fv[u] = s ? 1.0f : 0.0f;
                    if (s) v = 0.0;
                }
                #pragma unroll
                for (int q = 0; q < 4; ++q)
                    if (tb + q * 4 < tlim)
                        *(float4*)(py + tb + q * 4) =
                            make_float4(fv[q*4], fv[q*4+1], fv[q*4+2], fv[q*4+3]);
            }
        }
    }
}

extern "C" void kernel_launch(void* const* d_in, const int* in_sizes, int n_in,
                              void* d_out, int out_size, void* d_ws, size_t ws_size,
                              hipStream_t stream) {
    const float* x = (const float*)d_in[0];   // [64, 512, 500]
    const float* w = (const float*)d_in[1];   // [512, 512]
    float* y = (float*)d_out;                 // [64, 512, 500]
    (void)in_sizes; (void)n_in; (void)out_size;

    if (ws_size >= WS_FULL) {
        unsigned char* xt  = (unsigned char*)d_ws;
        unsigned char* wtb = (unsigned char*)d_ws + XT_BYTES;
        double* iw = (double*)((unsigned char*)d_ws + WS_SMALL);
        prep_xw<<<520, 256, 0, stream>>>(x, w, xt, wtb);
        snn_i8g<<<1024, 256, 0, stream>>>(xt, wtb, iw);     // 4 blocks/CU
        snn_scan<<<BO / 64, 64, 0, stream>>>(iw, y);
    } else if (ws_size >= WS_SMALL) {
        unsigned char* xt  = (unsigned char*)d_ws;
        unsigned char* wtb = (unsigned char*)d_ws + XT_BYTES;
        prep_xw<<<520, 256, 0, stream>>>(x, w, xt, wtb);
        snn_i8v5<<<512, 256, 0, stream>>>(xt, wtb, y);      // r11 proven
    } else {
        snn_v2<<<512, 256, 0, stream>>>(x, w, y);           // ws-free fallback
    }
}

// Round 15
// 384.001 us; speedup vs baseline: 1.9507x; 1.6535x over previous
//
#include <hip/hip_runtime.h>

// SNN layer on MI355X. i[t,b,o] = sum_k x[b,k,t]*w[k,o]; per-(b,o) sequential
// LIF scan over t; spikes (0/1) fp32 [B,O,T].
//
// Exact fixed-point i8-MFMA path (rounds 7-14 proven, absmax 0.0):
// X=rint(x*2^28) -> 4 signed i8 limbs, W=rint(w*2^15) -> 4 limbs; 13 limb
// pairs (p+q>=2) accumulated exactly in i32 (mfma_i32_16x16x64_i8), combined
// in fp64; eps_i ~ 3e-4 vs ~2e-3 budget.
//
// r14 post-mortem: launch_bounds(256,4) forced VGPR 144->64 + 700MB scratch
// spill (twice-reproduced failure mode; (256,2) reliably gives a clean
// 128-VGPR binary). At VGPR=128 + LDS=0 the HARDWARE already allows
// 16 waves/CU = 4 blocks/CU -- no launch-bounds coercion needed; r9/r11
// were 2 blocks/CU only because grid=512. This round: r14 byte-identical
// except snn_i8g launch_bounds (256,4) -> (256,2). Grid 1024 (t-split),
// 4 waves/SIMD spill-free -- the experiment r13/r14 failed to run.

#define NB 64
#define NI 512
#define NO 512
#define NT 500
#define BO (NB * NO)          // 32768 channels

typedef int v4i __attribute__((ext_vector_type(4)));
typedef double d2 __attribute__((ext_vector_type(2)));

#define XT_B_STRIDE 1048576   // bytes per batch in XT
#define P_STRIDE    262144    // bytes per limb plane
#define KB_STRIDE   8192      // bytes per k-block (512 rows * 16B)
#define XT_BYTES    67108864
#define WT_BYTES    1048576
#define IW_BYTES    ((size_t)NT * BO * 8)          // 131,072,000
#define WS_SMALL    ((size_t)XT_BYTES + WT_BYTES)  //  68,157,440
#define WS_FULL     (WS_SMALL + IW_BYTES)          // 199,229,440

// ============ prep: x transpose+limb-slice (blocks 0..511), w (512..519) ====
__global__ __launch_bounds__(256)
void prep_xw(const float* __restrict__ xg, const float* __restrict__ wg,
             unsigned char* __restrict__ xt, unsigned char* __restrict__ wtb) {
    __shared__ float xs[64][65];
    const int tid = threadIdx.x;
    const int sk  = tid >> 2;
    const int st  = (tid & 3) * 16;
    const int ct  = tid & 63;
    const int ckb = tid >> 6;

    if (blockIdx.x < 512) {
        const int b  = blockIdx.x >> 3;
        const int kc = (blockIdx.x & 7) * 64;
        for (int tc = 0; tc < 512; tc += 64) {
            __syncthreads();
            const float* px = xg + ((size_t)(b * NI + kc + sk)) * NT + tc + st;
            #pragma unroll
            for (int e = 0; e < 16; ++e)
                xs[sk][st + e] = (tc + st + e < NT) ? px[e] : 0.0f;
            __syncthreads();

            unsigned int u0[4] = {0,0,0,0}, u1[4] = {0,0,0,0};
            unsigned int u2[4] = {0,0,0,0}, u3[4] = {0,0,0,0};
            #pragma unroll
            for (int e = 0; e < 16; ++e) {
                const float xv = xs[ckb * 16 + e][ct];
                int X = __float2int_rn(xv * 268435456.0f);    // x * 2^28
                const int a0 = (X << 24) >> 24; X = (X - a0) >> 8;
                const int a1 = (X << 24) >> 24; X = (X - a1) >> 8;
                const int a2 = (X << 24) >> 24; const int a3 = (X - a2) >> 8;
                const int sh = (e & 3) * 8; const int d = e >> 2;
                u0[d] |= (unsigned)(a0 & 0xFF) << sh;
                u1[d] |= (unsigned)(a1 & 0xFF) << sh;
                u2[d] |= (unsigned)(a2 & 0xFF) << sh;
                u3[d] |= (unsigned)(a3 & 0xFF) << sh;
            }
            unsigned char* base = xt + (size_t)b * XT_B_STRIDE
                                  + (size_t)(kc / 16 + ckb) * KB_STRIDE
                                  + (size_t)(tc + ct) * 16;
            *(uint4*)(base)                = make_uint4(u0[0], u0[1], u0[2], u0[3]);
            *(uint4*)(base + P_STRIDE)     = make_uint4(u1[0], u1[1], u1[2], u1[3]);
            *(uint4*)(base + 2 * P_STRIDE) = make_uint4(u2[0], u2[1], u2[2], u2[3]);
            *(uint4*)(base + 3 * P_STRIDE) = make_uint4(u3[0], u3[1], u3[2], u3[3]);
        }
    } else {
        const int kc = (blockIdx.x - 512) * 64;
        for (int oc = 0; oc < 512; oc += 64) {
            __syncthreads();
            const float* pw = wg + (size_t)(kc + sk) * NO + oc + st;
            #pragma unroll
            for (int e = 0; e < 16; e += 4) {
                float4 f = *(const float4*)(pw + e);
                xs[sk][st + e + 0] = f.x; xs[sk][st + e + 1] = f.y;
                xs[sk][st + e + 2] = f.z; xs[sk][st + e + 3] = f.w;
            }
            __syncthreads();

            unsigned int u0[4] = {0,0,0,0}, u1[4] = {0,0,0,0};
            unsigned int u2[4] = {0,0,0,0}, u3[4] = {0,0,0,0};
            #pragma unroll
            for (int e = 0; e < 16; ++e) {
                const float wv = xs[ckb * 16 + e][ct];
                int X = __float2int_rn(wv * 32768.0f);        // w * 2^15
                const int a0 = (X << 24) >> 24; X = (X - a0) >> 8;
                const int a1 = (X << 24) >> 24; X = (X - a1) >> 8;
                const int a2 = (X << 24) >> 24; const int a3 = (X - a2) >> 8;
                const int sh = (e & 3) * 8; const int d = e >> 2;
                u0[d] |= (unsigned)(a0 & 0xFF) << sh;
                u1[d] |= (unsigned)(a1 & 0xFF) << sh;
                u2[d] |= (unsigned)(a2 & 0xFF) << sh;
                u3[d] |= (unsigned)(a3 & 0xFF) << sh;
            }
            unsigned char* base = wtb + (size_t)(kc / 16 + ckb) * KB_STRIDE
                                  + (size_t)(oc + ct) * 16;
            *(uint4*)(base)                = make_uint4(u0[0], u0[1], u0[2], u0[3]);
            *(uint4*)(base + P_STRIDE)     = make_uint4(u1[0], u1[1], u1[2], u1[3]);
            *(uint4*)(base + 2 * P_STRIDE) = make_uint4(u2[0], u2[1], u2[2], u2[3]);
            *(uint4*)(base + 3 * P_STRIDE) = make_uint4(u3[0], u3[1], u3[2], u3[3]);
        }
    }
}

#define MFMA_I8(a, b, c) __builtin_amdgcn_mfma_i32_16x16x64_i8(a, b, c, 0, 0, 0)

// ===== K1: t-split i8-MFMA GEMM -> iw fp64. No LDS/barriers.
// launch_bounds(256,2): allocator reliably picks 128 VGPR (r9/r11-proven);
// VGPR=128 + LDS=0 => HW allows 4 blocks/CU with grid 1024 = 4 waves/SIMD.
__global__ __launch_bounds__(256, 2)
void snn_i8g(const unsigned char* __restrict__ xt,
             const unsigned char* __restrict__ wtb,
             double* __restrict__ iw) {
    const int tid  = threadIdx.x;
    const int lane = tid & 63;
    const int wv   = tid >> 6;      // wave 0..3
    const int wt   = wv & 1;        // t-half of 64-t chunk (32 rows)
    const int wo   = wv >> 1;       // o-half (32 cols)
    const int lr   = lane & 15;
    const int lg   = lane >> 4;

    // bijective XCD swizzle (1024 blocks): a batch's 16 blocks share an XCD.
    const int L  = blockIdx.x;
    const int wg = (L & 7) * 128 + (L >> 3);
    const int b  = wg >> 4;             // 16 blocks per batch (8 o x 2 t-half)
    const int o0 = ((wg >> 1) & 7) * 64;
    const int th = wg & 1;              // t-half: t in [th*256, th*256+256)

    const unsigned char* xb = xt + (size_t)b * XT_B_STRIDE;
    const unsigned char* wb = wtb + (size_t)o0 * 16;

    for (int tc2 = 0; tc2 < 4; ++tc2) {         // 4 chunks of 64 t
        const int tch   = th * 4 + tc2;
        const int tbase = tch * 64 + wt * 32;   // wave's 32-t strip in XT

        v4i acc0[2][2], acc1[2][2], acc2[2][2], acc3[2][2], acc4[2][2];
        #pragma unroll
        for (int ta = 0; ta < 2; ++ta)
            #pragma unroll
            for (int oc = 0; oc < 2; ++oc) {
                acc0[ta][oc] = (v4i){0,0,0,0}; acc1[ta][oc] = (v4i){0,0,0,0};
                acc2[ta][oc] = (v4i){0,0,0,0}; acc3[ta][oc] = (v4i){0,0,0,0};
                acc4[ta][oc] = (v4i){0,0,0,0};
            }

        for (int kw = 0; kw < 8; ++kw) {        // plain r8-style loads; TLP hides
            const size_t kb0 = (size_t)(kw * 4 + lg) * KB_STRIDE;
            v4i aF[2][4], bF[2][4];
            #pragma unroll
            for (int p = 0; p < 4; ++p) {
                const size_t pp = (size_t)p * P_STRIDE + kb0;
                #pragma unroll
                for (int ta = 0; ta < 2; ++ta)
                    aF[ta][p] = *(const v4i*)(xb + pp
                                 + (size_t)(tbase + ta * 16 + lr) * 16);
                #pragma unroll
                for (int oc = 0; oc < 2; ++oc)
                    bF[oc][p] = *(const v4i*)(wb + pp
                                 + (size_t)(wo * 32 + oc * 16 + lr) * 16);
            }
            #pragma unroll
            for (int ta = 0; ta < 2; ++ta)
                #pragma unroll
                for (int oc = 0; oc < 2; ++oc) {
                    acc0[ta][oc] = MFMA_I8(aF[ta][0], bF[oc][2], acc0[ta][oc]);
                    acc0[ta][oc] = MFMA_I8(aF[ta][1], bF[oc][1], acc0[ta][oc]);
                    acc0[ta][oc] = MFMA_I8(aF[ta][2], bF[oc][0], acc0[ta][oc]);
                    acc1[ta][oc] = MFMA_I8(aF[ta][0], bF[oc][3], acc1[ta][oc]);
                    acc1[ta][oc] = MFMA_I8(aF[ta][1], bF[oc][2], acc1[ta][oc]);
                    acc1[ta][oc] = MFMA_I8(aF[ta][2], bF[oc][1], acc1[ta][oc]);
                    acc1[ta][oc] = MFMA_I8(aF[ta][3], bF[oc][0], acc1[ta][oc]);
                    acc2[ta][oc] = MFMA_I8(aF[ta][1], bF[oc][3], acc2[ta][oc]);
                    acc2[ta][oc] = MFMA_I8(aF[ta][2], bF[oc][2], acc2[ta][oc]);
                    acc2[ta][oc] = MFMA_I8(aF[ta][3], bF[oc][1], acc2[ta][oc]);
                    acc3[ta][oc] = MFMA_I8(aF[ta][2], bF[oc][3], acc3[ta][oc]);
                    acc3[ta][oc] = MFMA_I8(aF[ta][3], bF[oc][2], acc3[ta][oc]);
                    acc4[ta][oc] = MFMA_I8(aF[ta][3], bF[oc][3], acc4[ta][oc]);
                }
        }

        // combine limbs in fp64; write straight to iw[t][b*NO+o] (128B segs)
        #pragma unroll
        for (int ta = 0; ta < 2; ++ta)
            #pragma unroll
            for (int oc = 0; oc < 2; ++oc) {
                const int o_loc = wo * 32 + oc * 16 + lr;
                #pragma unroll
                for (int r = 0; r < 4; ++r) {
                    const int t = tbase + ta * 16 + lg * 4 + r;
                    if (t < NT) {
                        const double iv =
                              (double)acc0[ta][oc][r] * 0x1p-27
                            + (double)acc1[ta][oc][r] * 0x1p-19
                            + (double)acc2[ta][oc][r] * 0x1p-11
                            + (double)acc3[ta][oc][r] * 0x1p-3
                            + (double)acc4[ta][oc][r] * 0x1p+5;
                        iw[(size_t)t * BO + b * NO + o0 + o_loc] = iv;
                    }
                }
            }
    }
}

// ===== K2: sequential LIF scan (r5-proven) =====
#define SB 20                 // 500 = 25*20
__global__ __launch_bounds__(64)
void snn_scan(const double* __restrict__ iw, float* __restrict__ yg) {
    const int ch = blockIdx.x * 64 + threadIdx.x;   // b*512+o
    const double alpha = 0.001 / 50.0;
    double v = 0.0;
    float* py = yg + (size_t)ch * NT;

    for (int tb = 0; tb < NT; tb += SB) {
        double iv[SB];
        #pragma unroll
        for (int u = 0; u < SB; ++u) iv[u] = iw[(size_t)(tb + u) * BO + ch];
        float fv[SB];
        #pragma unroll
        for (int u = 0; u < SB; ++u) {
            v += (iv[u] - v) * alpha;
            const bool s = (v >= 1.0);
            fv[u] = s ? 1.0f : 0.0f;
            if (s) v = 0.0;
        }
        #pragma unroll
        for (int q = 0; q < SB / 4; ++q)
            *(float4*)(py + tb + 4 * q) =
                make_float4(fv[4*q], fv[4*q+1], fv[4*q+2], fv[4*q+3]);
    }
}

// ===== fallback A: r11 fused kernel (225us proven) =====
__global__ __launch_bounds__(256, 2)
void snn_i8v5(const unsigned char* __restrict__ xt,
              const unsigned char* __restrict__ wtb,
              float* __restrict__ yg) {
    __shared__ double ib[64][66];

    const int tid  = threadIdx.x;
    const int lane = tid & 63;
    const int wv   = tid >> 6;
    const int wt   = wv & 1;
    const int wo   = wv >> 1;
    const int lr   = lane & 15;
    const int lg   = lane >> 4;

    const int L  = blockIdx.x;
    const int b  = (L & 7) + ((L >> 6) << 3);
    const int o0 = ((L >> 3) & 7) * 64;

    const unsigned char* xb = xt + (size_t)b * XT_B_STRIDE;
    const unsigned char* wb = wtb + (size_t)o0 * 16;

    const double alpha = 0.001 / 50.0;
    double v = 0.0;

    for (int tc = 0; tc < 8; ++tc) {
        v4i acc0[2][2], acc1[2][2], acc2[2][2], acc3[2][2], acc4[2][2];
        #pragma unroll
        for (int ta = 0; ta < 2; ++ta)
            #pragma unroll
            for (int oc = 0; oc < 2; ++oc) {
                acc0[ta][oc] = (v4i){0,0,0,0}; acc1[ta][oc] = (v4i){0,0,0,0};
                acc2[ta][oc] = (v4i){0,0,0,0}; acc3[ta][oc] = (v4i){0,0,0,0};
                acc4[ta][oc] = (v4i){0,0,0,0};
            }
        const int tbase = tc * 64 + wt * 32;

        for (int kw = 0; kw < 8; ++kw) {
            const size_t kb0 = (size_t)(kw * 4 + lg) * KB_STRIDE;
            v4i aF[2][4], bF[2][4];
            #pragma unroll
            for (int p = 0; p < 4; ++p) {
                const size_t pp = (size_t)p * P_STRIDE + kb0;
                #pragma unroll
                for (int ta = 0; ta < 2; ++ta)
                    aF[ta][p] = *(const v4i*)(xb + pp
                                 + (size_t)(tbase + ta * 16 + lr) * 16);
                #pragma unroll
                for (int oc = 0; oc < 2; ++oc)
                    bF[oc][p] = *(const v4i*)(wb + pp
                                 + (size_t)(wo * 32 + oc * 16 + lr) * 16);
            }
            #pragma unroll
            for (int ta = 0; ta < 2; ++ta)
                #pragma unroll
                for (int oc = 0; oc < 2; ++oc) {
                    acc0[ta][oc] = MFMA_I8(aF[ta][0], bF[oc][2], acc0[ta][oc]);
                    acc0[ta][oc] = MFMA_I8(aF[ta][1], bF[oc][1], acc0[ta][oc]);
                    acc0[ta][oc] = MFMA_I8(aF[ta][2], bF[oc][0], acc0[ta][oc]);
                    acc1[ta][oc] = MFMA_I8(aF[ta][0], bF[oc][3], acc1[ta][oc]);
                    acc1[ta][oc] = MFMA_I8(aF[ta][1], bF[oc][2], acc1[ta][oc]);
                    acc1[ta][oc] = MFMA_I8(aF[ta][2], bF[oc][1], acc1[ta][oc]);
                    acc1[ta][oc] = MFMA_I8(aF[ta][3], bF[oc][0], acc1[ta][oc]);
                    acc2[ta][oc] = MFMA_I8(aF[ta][1], bF[oc][3], acc2[ta][oc]);
                    acc2[ta][oc] = MFMA_I8(aF[ta][2], bF[oc][2], acc2[ta][oc]);
                    acc2[ta][oc] = MFMA_I8(aF[ta][3], bF[oc][1], acc2[ta][oc]);
                    acc3[ta][oc] = MFMA_I8(aF[ta][2], bF[oc][3], acc3[ta][oc]);
                    acc3[ta][oc] = MFMA_I8(aF[ta][3], bF[oc][2], acc3[ta][oc]);
                    acc4[ta][oc] = MFMA_I8(aF[ta][3], bF[oc][3], acc4[ta][oc]);
                }
        }

        __syncthreads();
        #pragma unroll
        for (int ta = 0; ta < 2; ++ta)
            #pragma unroll
            for (int oc = 0; oc < 2; ++oc) {
                const int o_loc = wo * 32 + oc * 16 + lr;
                #pragma unroll
                for (int r = 0; r < 4; ++r) {
                    const double iv =
                          (double)acc0[ta][oc][r] * 0x1p-27
                        + (double)acc1[ta][oc][r] * 0x1p-19
                        + (double)acc2[ta][oc][r] * 0x1p-11
                        + (double)acc3[ta][oc][r] * 0x1p-3
                        + (double)acc4[ta][oc][r] * 0x1p+5;
                    ib[wt * 32 + ta * 16 + lg * 4 + r][o_loc] = iv;
                }
            }
        __syncthreads();

        if (lane < 16) {
            const int ol = wv * 16 + lane;
            float* py = yg + ((size_t)(b * NO) + o0 + ol) * NT + tc * 64;
            #pragma unroll
            for (int tb = 0; tb < 4; ++tb) {
                double iv[16];
                #pragma unroll
                for (int u = 0; u < 16; ++u) iv[u] = ib[tb * 16 + u][ol];
                float fv[16];
                #pragma unroll
                for (int u = 0; u < 16; ++u) {
                    v += (iv[u] - v) * alpha;
                    const bool s = (v >= 1.0);
                    fv[u] = s ? 1.0f : 0.0f;
                    if (s) v = 0.0;
                }
                const int tg = tc * 64 + tb * 16;
                #pragma unroll
                for (int q = 0; q < 4; ++q)
                    if (tg + q * 4 < NT)
                        *(float4*)(py + tb * 16 + q * 4) =
                            make_float4(fv[q*4], fv[q*4+1], fv[q*4+2], fv[q*4+3]);
            }
        }
    }
}

// ===== fallback B: r4 fused fp64 kernel (ws-free, proven) =====
#define OT 64
#define TT 64
#define KC 32
#define TP (TT + 2)
#define OP (OT + 2)

__global__ __launch_bounds__(256, 2)
void snn_v2(const float* __restrict__ xg, const float* __restrict__ wg,
            float* __restrict__ yg) {
    __shared__ double smem[KC * TP + KC * OP];
    double (*xs)[TP]  = (double(*)[TP])smem;
    double (*wsh)[OP] = (double(*)[OP])(smem + KC * TP);
    double (*ib)[OP]  = (double(*)[OP])smem;

    const int tid = threadIdx.x;
    const int p2  = (tid & 31) * 2;
    const int t0  = (tid >> 5) * 8;
    const int L   = blockIdx.x;
    const int b   = (L & 7) + ((L >> 6) << 3);
    const int o0  = ((L >> 3) & 7) * OT;
    const int sk  = tid >> 3;
    const int se  = (tid & 7) * 8;
    const double alpha = 0.001 / 50.0;
    double v = 0.0;

    for (int tc = 0; tc < NT; tc += TT) {
        const int tlim = (NT - tc < TT) ? (NT - tc) : TT;
        double a0[8], a1[8];
        #pragma unroll
        for (int j = 0; j < 8; ++j) { a0[j] = 0.0; a1[j] = 0.0; }

        for (int kc = 0; kc < NI; kc += KC) {
            __syncthreads();
            {
                const float* px = xg + ((size_t)(b * NI + kc + sk)) * NT + tc + se;
                double* dx = &xs[sk][se];
                if (tlim == TT) {
                    #pragma unroll
                    for (int e = 0; e < 2; ++e) {
                        float4 f = ((const float4*)px)[e];
                        d2 lo = {(double)f.x, (double)f.y};
                        d2 hi = {(double)f.z, (double)f.w};
                        *(d2*)(dx + e * 4) = lo; *(d2*)(dx + e * 4 + 2) = hi;
                    }
                } else {
                    #pragma unroll
                    for (int e = 0; e < 8; ++e) {
                        double val = 0.0;
                        if (se + e < tlim) val = (double)px[e];
                        dx[e] = val;
                    }
                }
            }
            {
                const float* pw = wg + (size_t)(kc + sk) * NO + o0 + se;
                double* dw = &wsh[sk][se];
                #pragma unroll
                for (int e = 0; e < 2; ++e) {
                    float4 f = ((const float4*)pw)[e];
                    d2 lo = {(double)f.x, (double)f.y};
                    d2 hi = {(double)f.z, (double)f.w};
                    *(d2*)(dw + e * 4) = lo; *(d2*)(dw + e * 4 + 2) = hi;
                }
            }
            __syncthreads();
            #pragma unroll 4
            for (int k = 0; k < KC; ++k) {
                const d2 w2 = *(const d2*)&wsh[k][p2];
                double x8[8];
                #pragma unroll
                for (int e = 0; e < 4; ++e)
                    *(d2*)&x8[e * 2] = *(const d2*)&xs[k][t0 + e * 2];
                #pragma unroll
                for (int j = 0; j < 8; ++j) {
                    a0[j] += x8[j] * w2[0];
                    a1[j] += x8[j] * w2[1];
                }
            }
        }
        __syncthreads();
        #pragma unroll
        for (int j = 0; j < 8; ++j) {
            d2 c = {a0[j], a1[j]};
            *(d2*)&ib[t0 + j][p2] = c;
        }
        __syncthreads();
        if (tid < 64) {
            float* py = yg + ((size_t)(b * NO + o0 + tid)) * NT + tc;
            for (int tb = 0; tb < TT; tb += 16) {
                double iv[16];
                #pragma unroll
                for (int u = 0; u < 16; ++u) iv[u] = ib[tb + u][tid];
                float fv[16];
                #pragma unroll
                for (int u = 0; u < 16; ++u) {
                    v += (iv[u] - v) * alpha;
                    const bool s = (v >= 1.0);
                    fv[u] = s ? 1.0f : 0.0f;
                    if (s) v = 0.0;
                }
                #pragma unroll
                for (int q = 0; q < 4; ++q)
                    if (tb + q * 4 < tlim)
                        *(float4*)(py + tb + q * 4) =
                            make_float4(fv[q*4], fv[q*4+1], fv[q*4+2], fv[q*4+3]);
            }
        }
    }
}

extern "C" void kernel_launch(void* const* d_in, const int* in_sizes, int n_in,
                              void* d_out, int out_size, void* d_ws, size_t ws_size,
                              hipStream_t stream) {
    const float* x = (const float*)d_in[0];   // [64, 512, 500]
    const float* w = (const float*)d_in[1];   // [512, 512]
    float* y = (float*)d_out;                 // [64, 512, 500]
    (void)in_sizes; (void)n_in; (void)out_size;

    if (ws_size >= WS_FULL) {
        unsigned char* xt  = (unsigned char*)d_ws;
        unsigned char* wtb = (unsigned char*)d_ws + XT_BYTES;
        double* iw = (double*)((unsigned char*)d_ws + WS_SMALL);
        prep_xw<<<520, 256, 0, stream>>>(x, w, xt, wtb);
        snn_i8g<<<1024, 256, 0, stream>>>(xt, wtb, iw);     // 4 blocks/CU (HW)
        snn_scan<<<BO / 64, 64, 0, stream>>>(iw, y);
    } else if (ws_size >= WS_SMALL) {
        unsigned char* xt  = (unsigned char*)d_ws;
        unsigned char* wtb = (unsigned char*)d_ws + XT_BYTES;
        prep_xw<<<520, 256, 0, stream>>>(x, w, xt, wtb);
        snn_i8v5<<<512, 256, 0, stream>>>(xt, wtb, y);      // r11 proven
    } else {
        snn_v2<<<512, 256, 0, stream>>>(x, w, y);           // ws-free fallback
    }
}

// Round 16
// 180.458 us; speedup vs baseline: 4.1510x; 2.1279x over previous
//
#include <hip/hip_runtime.h>

// SNN layer on MI355X. i[t,b,o] = sum_k x[b,k,t]*w[k,o]; per-(b,o) sequential
// LIF scan over t; spikes (0/1) fp32 [B,O,T].
//
// FINAL: locked to the measured optimum (r11 config, 240.6us total) plus a
// bit-identical MFMA reorder (13 limb-pair slots x 4 independent (ta,oc)
// MFMAs -> no adjacent same-accumulator RAW chains).
//
// Exact fixed-point i8-MFMA path (rounds 7-15 proven, absmax 0.0):
// X=rint(x*2^28) -> 4 signed i8 limbs, W=rint(w*2^15) -> 4 limbs; 13 limb
// pairs (p+q>=2) accumulated exactly in i32 (mfma_i32_16x16x64_i8), combined
// in fp64; eps_i ~ 3e-4 vs ~2e-3 budget. Integer accumulation is exact ->
// instruction order cannot change results.
//
// Structure ledger (why this config): register-direct fragments from a
// fragment-layout workspace (XT/WT), 32t x 32o wave tile, fused scan.
// Falsified alternatives: reg ping-pong (r9, compiler collapsed), LDS
// pipeline (r10, barrier-serialized), sched_barrier prefetch (r11, vmcnt
// forced), smaller tile + waves (r12, 2x traffic), 8-wave blocks (r13/r14
// spilled at launch_bounds<=... ; r15 clean but occupancy didn't rise).

#define NB 64
#define NI 512
#define NO 512
#define NT 500

typedef int v4i __attribute__((ext_vector_type(4)));
typedef double d2 __attribute__((ext_vector_type(2)));

#define XT_B_STRIDE 1048576   // bytes per batch in XT
#define P_STRIDE    262144    // bytes per limb plane
#define KB_STRIDE   8192      // bytes per k-block (512 rows * 16B)
#define XT_BYTES    67108864
#define WT_BYTES    1048576
#define WS_NEED     ((size_t)XT_BYTES + WT_BYTES)   // 68,157,440

// ============ prep: x transpose+limb-slice (blocks 0..511), w (512..519) ====
__global__ __launch_bounds__(256)
void prep_xw(const float* __restrict__ xg, const float* __restrict__ wg,
             unsigned char* __restrict__ xt, unsigned char* __restrict__ wtb) {
    __shared__ float xs[64][65];
    const int tid = threadIdx.x;
    const int sk  = tid >> 2;
    const int st  = (tid & 3) * 16;
    const int ct  = tid & 63;
    const int ckb = tid >> 6;

    if (blockIdx.x < 512) {
        const int b  = blockIdx.x >> 3;
        const int kc = (blockIdx.x & 7) * 64;
        for (int tc = 0; tc < 512; tc += 64) {
            __syncthreads();
            const float* px = xg + ((size_t)(b * NI + kc + sk)) * NT + tc + st;
            #pragma unroll
            for (int e = 0; e < 16; ++e)
                xs[sk][st + e] = (tc + st + e < NT) ? px[e] : 0.0f;
            __syncthreads();

            unsigned int u0[4] = {0,0,0,0}, u1[4] = {0,0,0,0};
            unsigned int u2[4] = {0,0,0,0}, u3[4] = {0,0,0,0};
            #pragma unroll
            for (int e = 0; e < 16; ++e) {
                const float xv = xs[ckb * 16 + e][ct];
                int X = __float2int_rn(xv * 268435456.0f);    // x * 2^28
                const int a0 = (X << 24) >> 24; X = (X - a0) >> 8;
                const int a1 = (X << 24) >> 24; X = (X - a1) >> 8;
                const int a2 = (X << 24) >> 24; const int a3 = (X - a2) >> 8;
                const int sh = (e & 3) * 8; const int d = e >> 2;
                u0[d] |= (unsigned)(a0 & 0xFF) << sh;
                u1[d] |= (unsigned)(a1 & 0xFF) << sh;
                u2[d] |= (unsigned)(a2 & 0xFF) << sh;
                u3[d] |= (unsigned)(a3 & 0xFF) << sh;
            }
            unsigned char* base = xt + (size_t)b * XT_B_STRIDE
                                  + (size_t)(kc / 16 + ckb) * KB_STRIDE
                                  + (size_t)(tc + ct) * 16;
            *(uint4*)(base)                = make_uint4(u0[0], u0[1], u0[2], u0[3]);
            *(uint4*)(base + P_STRIDE)     = make_uint4(u1[0], u1[1], u1[2], u1[3]);
            *(uint4*)(base + 2 * P_STRIDE) = make_uint4(u2[0], u2[1], u2[2], u2[3]);
            *(uint4*)(base + 3 * P_STRIDE) = make_uint4(u3[0], u3[1], u3[2], u3[3]);
        }
    } else {
        const int kc = (blockIdx.x - 512) * 64;
        for (int oc = 0; oc < 512; oc += 64) {
            __syncthreads();
            const float* pw = wg + (size_t)(kc + sk) * NO + oc + st;
            #pragma unroll
            for (int e = 0; e < 16; e += 4) {
                float4 f = *(const float4*)(pw + e);
                xs[sk][st + e + 0] = f.x; xs[sk][st + e + 1] = f.y;
                xs[sk][st + e + 2] = f.z; xs[sk][st + e + 3] = f.w;
            }
            __syncthreads();

            unsigned int u0[4] = {0,0,0,0}, u1[4] = {0,0,0,0};
            unsigned int u2[4] = {0,0,0,0}, u3[4] = {0,0,0,0};
            #pragma unroll
            for (int e = 0; e < 16; ++e) {
                const float wv = xs[ckb * 16 + e][ct];
                int X = __float2int_rn(wv * 32768.0f);        // w * 2^15
                const int a0 = (X << 24) >> 24; X = (X - a0) >> 8;
                const int a1 = (X << 24) >> 24; X = (X - a1) >> 8;
                const int a2 = (X << 24) >> 24; const int a3 = (X - a2) >> 8;
                const int sh = (e & 3) * 8; const int d = e >> 2;
                u0[d] |= (unsigned)(a0 & 0xFF) << sh;
                u1[d] |= (unsigned)(a1 & 0xFF) << sh;
                u2[d] |= (unsigned)(a2 & 0xFF) << sh;
                u3[d] |= (unsigned)(a3 & 0xFF) << sh;
            }
            unsigned char* base = wtb + (size_t)(kc / 16 + ckb) * KB_STRIDE
                                  + (size_t)(oc + ct) * 16;
            *(uint4*)(base)                = make_uint4(u0[0], u0[1], u0[2], u0[3]);
            *(uint4*)(base + P_STRIDE)     = make_uint4(u1[0], u1[1], u1[2], u1[3]);
            *(uint4*)(base + 2 * P_STRIDE) = make_uint4(u2[0], u2[1], u2[2], u2[3]);
            *(uint4*)(base + 3 * P_STRIDE) = make_uint4(u3[0], u3[1], u3[2], u3[3]);
        }
    }
}

// ====== main: register-direct i8-MFMA GEMM + fused scan (r11 structure) ======
#define MFMA_I8(a, b, c) __builtin_amdgcn_mfma_i32_16x16x64_i8(a, b, c, 0, 0, 0)

// one limb-pair slot: 4 independent MFMAs (ta,oc); no same-acc adjacency
#define SLOT(ACC, AI, BI)                                              \
    _Pragma("unroll")                                                  \
    for (int ta = 0; ta < 2; ++ta) {                                   \
        _Pragma("unroll")                                              \
        for (int oc = 0; oc < 2; ++oc)                                 \
            ACC[ta][oc] = MFMA_I8(aF[ta][AI], bF[oc][BI], ACC[ta][oc]);\
    }

__global__ __launch_bounds__(256, 2)
void snn_i8v5(const unsigned char* __restrict__ xt,
              const unsigned char* __restrict__ wtb,
              float* __restrict__ yg) {
    __shared__ double ib[64][66];        // 33,792 B

    const int tid  = threadIdx.x;
    const int lane = tid & 63;
    const int wv   = tid >> 6;      // wave 0..3
    const int wt   = wv & 1;        // t-half (32 rows)
    const int wo   = wv >> 1;       // o-half (32 cols)
    const int lr   = lane & 15;
    const int lg   = lane >> 4;

    // XCD swizzle (proven): 8 o-tiles of one batch share an XCD.
    const int L  = blockIdx.x;
    const int b  = (L & 7) + ((L >> 6) << 3);
    const int o0 = ((L >> 3) & 7) * 64;

    const unsigned char* xb = xt + (size_t)b * XT_B_STRIDE;
    const unsigned char* wb = wtb + (size_t)o0 * 16;

    const double alpha = 0.001 / 50.0;
    double v = 0.0;                 // scan state (lanes<16 of each wave)

    for (int tc = 0; tc < 8; ++tc) {            // 8 chunks of 64 t (512 padded)
        v4i acc0[2][2], acc1[2][2], acc2[2][2], acc3[2][2], acc4[2][2];
        #pragma unroll
        for (int ta = 0; ta < 2; ++ta)
            #pragma unroll
            for (int oc = 0; oc < 2; ++oc) {
                acc0[ta][oc] = (v4i){0,0,0,0}; acc1[ta][oc] = (v4i){0,0,0,0};
                acc2[ta][oc] = (v4i){0,0,0,0}; acc3[ta][oc] = (v4i){0,0,0,0};
                acc4[ta][oc] = (v4i){0,0,0,0};
            }
        const int tbase = tc * 64 + wt * 32;

        for (int kw = 0; kw < 8; ++kw) {
            const size_t kb0 = (size_t)(kw * 4 + lg) * KB_STRIDE;
            v4i aF[2][4], bF[2][4];
            #pragma unroll
            for (int p = 0; p < 4; ++p) {
                const size_t pp = (size_t)p * P_STRIDE + kb0;
                #pragma unroll
                for (int ta = 0; ta < 2; ++ta)
                    aF[ta][p] = *(const v4i*)(xb + pp
                                 + (size_t)(tbase + ta * 16 + lr) * 16);
                #pragma unroll
                for (int oc = 0; oc < 2; ++oc)
                    bF[oc][p] = *(const v4i*)(wb + pp
                                 + (size_t)(wo * 32 + oc * 16 + lr) * 16);
            }
            // 13 limb-pair slots, interleaved across accumulators:
            SLOT(acc0, 0, 2)  SLOT(acc1, 0, 3)  SLOT(acc2, 1, 3)
            SLOT(acc3, 2, 3)  SLOT(acc4, 3, 3)
            SLOT(acc0, 1, 1)  SLOT(acc1, 1, 2)  SLOT(acc2, 2, 2)
            SLOT(acc3, 3, 2)
            SLOT(acc0, 2, 0)  SLOT(acc1, 2, 1)  SLOT(acc2, 3, 1)
            SLOT(acc1, 3, 0)
        }

        __syncthreads();   // previous chunk's scan reads complete
        // D: col = lane&15 (o), row = 4*(lane>>4)+reg (t) -- HW-verified.
        #pragma unroll
        for (int ta = 0; ta < 2; ++ta)
            #pragma unroll
            for (int oc = 0; oc < 2; ++oc) {
                const int o_loc = wo * 32 + oc * 16 + lr;
                #pragma unroll
                for (int r = 0; r < 4; ++r) {
                    const double iv =
                          (double)acc0[ta][oc][r] * 0x1p-27
                        + (double)acc1[ta][oc][r] * 0x1p-19
                        + (double)acc2[ta][oc][r] * 0x1p-11
                        + (double)acc3[ta][oc][r] * 0x1p-3
                        + (double)acc4[ta][oc][r] * 0x1p+5;
                    ib[wt * 32 + ta * 16 + lg * 4 + r][o_loc] = iv;
                }
            }
        __syncthreads();

        // ---- scan: each wave handles its 16 o-channels (lanes 0..15) ----
        if (lane < 16) {
            const int ol = wv * 16 + lane;               // local o 0..63
            float* py = yg + ((size_t)(b * NO) + o0 + ol) * NT + tc * 64;
            #pragma unroll
            for (int tb = 0; tb < 4; ++tb) {
                double iv[16];
                #pragma unroll
                for (int u = 0; u < 16; ++u) iv[u] = ib[tb * 16 + u][ol];
                float fv[16];
                #pragma unroll
                for (int u = 0; u < 16; ++u) {
                    v += (iv[u] - v) * alpha;
                    const bool s = (v >= 1.0);
                    fv[u] = s ? 1.0f : 0.0f;
                    if (s) v = 0.0;
                }
                const int tg = tc * 64 + tb * 16;
                #pragma unroll
                for (int q = 0; q < 4; ++q)
                    if (tg + q * 4 < NT)
                        *(float4*)(py + tb * 16 + q * 4) =
                            make_float4(fv[q*4], fv[q*4+1], fv[q*4+2], fv[q*4+3]);
            }
        }
    }
}

// ============ fallback: round-4 fused fp64 kernel (ws-free, proven) ============
#define OT 64
#define TT 64
#define KC 32
#define TP (TT + 2)
#define OP (OT + 2)

__global__ __launch_bounds__(256, 2)
void snn_v2(const float* __restrict__ xg, const float* __restrict__ wg,
            float* __restrict__ yg) {
    __shared__ double smem[KC * TP + KC * OP];
    double (*xs)[TP]  = (double(*)[TP])smem;
    double (*wsh)[OP] = (double(*)[OP])(smem + KC * TP);
    double (*ib)[OP]  = (double(*)[OP])smem;

    const int tid = threadIdx.x;
    const int p2  = (tid & 31) * 2;
    const int t0  = (tid >> 5) * 8;
    const int L   = blockIdx.x;
    const int b   = (L & 7) + ((L >> 6) << 3);
    const int o0  = ((L >> 3) & 7) * OT;
    const int sk  = tid >> 3;
    const int se  = (tid & 7) * 8;
    const double alpha = 0.001 / 50.0;
    double v = 0.0;

    for (int tc = 0; tc < NT; tc += TT) {
        const int tlim = (NT - tc < TT) ? (NT - tc) : TT;
        double a0[8], a1[8];
        #pragma unroll
        for (int j = 0; j < 8; ++j) { a0[j] = 0.0; a1[j] = 0.0; }

        for (int kc = 0; kc < NI; kc += KC) {
            __syncthreads();
            {
                const float* px = xg + ((size_t)(b * NI + kc + sk)) * NT + tc + se;
                double* dx = &xs[sk][se];
                if (tlim == TT) {
                    #pragma unroll
                    for (int e = 0; e < 2; ++e) {
                        float4 f = ((const float4*)px)[e];
                        d2 lo = {(double)f.x, (double)f.y};
                        d2 hi = {(double)f.z, (double)f.w};
                        *(d2*)(dx + e * 4) = lo; *(d2*)(dx + e * 4 + 2) = hi;
                    }
                } else {
                    #pragma unroll
                    for (int e = 0; e < 8; ++e) {
                        double val = 0.0;
                        if (se + e < tlim) val = (double)px[e];
                        dx[e] = val;
                    }
                }
            }
            {
                const float* pw = wg + (size_t)(kc + sk) * NO + o0 + se;
                double* dw = &wsh[sk][se];
                #pragma unroll
                for (int e = 0; e < 2; ++e) {
                    float4 f = ((const float4*)pw)[e];
                    d2 lo = {(double)f.x, (double)f.y};
                    d2 hi = {(double)f.z, (double)f.w};
                    *(d2*)(dw + e * 4) = lo; *(d2*)(dw + e * 4 + 2) = hi;
                }
            }
            __syncthreads();
            #pragma unroll 4
            for (int k = 0; k < KC; ++k) {
                const d2 w2 = *(const d2*)&wsh[k][p2];
                double x8[8];
                #pragma unroll
                for (int e = 0; e < 4; ++e)
                    *(d2*)&x8[e * 2] = *(const d2*)&xs[k][t0 + e * 2];
                #pragma unroll
                for (int j = 0; j < 8; ++j) {
                    a0[j] += x8[j] * w2[0];
                    a1[j] += x8[j] * w2[1];
                }
            }
        }
        __syncthreads();
        #pragma unroll
        for (int j = 0; j < 8; ++j) {
            d2 c = {a0[j], a1[j]};
            *(d2*)&ib[t0 + j][p2] = c;
        }
        __syncthreads();
        if (tid < 64) {
            float* py = yg + ((size_t)(b * NO + o0 + tid)) * NT + tc;
            for (int tb = 0; tb < TT; tb += 16) {
                double iv[16];
                #pragma unroll
                for (int u = 0; u < 16; ++u) iv[u] = ib[tb + u][tid];
                float fv[16];
                #pragma unroll
                for (int u = 0; u < 16; ++u) {
                    v += (iv[u] - v) * alpha;
                    const bool s = (v >= 1.0);
                    fv[u] = s ? 1.0f : 0.0f;
                    if (s) v = 0.0;
                }
                #pragma unroll
                for (int q = 0; q < 4; ++q)
                    if (tb + q * 4 < tlim)
                        *(float4*)(py + tb + q * 4) =
                            make_float4(fv[q*4], fv[q*4+1], fv[q*4+2], fv[q*4+3]);
            }
        }
    }
}

extern "C" void kernel_launch(void* const* d_in, const int* in_sizes, int n_in,
                              void* d_out, int out_size, void* d_ws, size_t ws_size,
                              hipStream_t stream) {
    const float* x = (const float*)d_in[0];   // [64, 512, 500]
    const float* w = (const float*)d_in[1];   // [512, 512]
    float* y = (float*)d_out;                 // [64, 512, 500]
    (void)in_sizes; (void)n_in; (void)out_size;

    if (ws_size >= WS_NEED) {
        unsigned char* xt  = (unsigned char*)d_ws;
        unsigned char* wtb = (unsigned char*)d_ws + XT_BYTES;
        prep_xw<<<520, 256, 0, stream>>>(x, w, xt, wtb);
        snn_i8v5<<<512, 256, 0, stream>>>(xt, wtb, y);      // r11-proven path
    } else {
        snn_v2<<<512, 256, 0, stream>>>(x, w, y);           // ws-free fallback
    }
}